// Round 1
// baseline (658.856 us; speedup 1.0000x reference)
//
#include <hip/hip_runtime.h>
#include <hip/hip_bf16.h>
#include <math.h>

// ---------------------------------------------------------------------------
// QuantumProcessingLayer: out = tanh(concat(f(x), f(x)^2) @ W + b)
//   f(x) = tanh(2pi x) + 0.1*sin(2pi x)*cos(pi x)
// M=16384 (B*S), F=2048, K=4096 (2F), N=2048 (U). fp32 in/out, bf16 MFMA core.
// ---------------------------------------------------------------------------

typedef __bf16 b16x8 __attribute__((ext_vector_type(8)));
typedef float f32x4 __attribute__((ext_vector_type(4)));

constexpr int Mdim = 16384;
constexpr int Fdim = 2048;
constexpr int Kdim = 4096;
constexpr int Ndim = 2048;

#define TWO_PI_F 6.28318530717958647692f

__device__ __forceinline__ float fast_tanh(float x) {
  float ax = fabsf(x);
  float e = __expf(-2.0f * ax);
  float t = (1.0f - e) / (1.0f + e);
  return copysignf(t, x);
}

// ---------------- prologue: feats[m][k] (bf16), k<F: qe, k>=F: qe^2 ---------
struct __align__(8) B4 { __bf16 v[4]; };

__global__ void feats_kernel(const float* __restrict__ x, __bf16* __restrict__ feats) {
  int idx = blockIdx.x * blockDim.x + threadIdx.x;  // one thread per 4 elems
  int i4 = idx << 2;
  float4 xv = reinterpret_cast<const float4*>(x)[idx];
  float q[4] = {xv.x, xv.y, xv.z, xv.w};
  B4 qe, en;
#pragma unroll
  for (int j = 0; j < 4; ++j) {
    float qp = TWO_PI_F * q[j];
    float t = fast_tanh(qp);
    float v = t + 0.1f * (__sinf(qp) * __cosf(0.5f * qp));
    qe.v[j] = (__bf16)v;
    en.v[j] = (__bf16)(v * v);
  }
  int m = i4 >> 11;          // / Fdim
  int f = i4 & (Fdim - 1);
  size_t base = (size_t)m * Kdim + f;
  *reinterpret_cast<B4*>(feats + base) = qe;
  *reinterpret_cast<B4*>(feats + base + Fdim) = en;
}

// ---------------- W [K][N] fp32  ->  Wt [N][K] bf16 ------------------------
__global__ void wtrans_kernel(const float* __restrict__ W, __bf16* __restrict__ Wt) {
  __shared__ float tile[32][33];
  int bn = blockIdx.x;   // N/32 = 64
  int bk = blockIdx.y;   // K/32 = 128
  int tx = threadIdx.x;  // 0..31
  int ty = threadIdx.y;  // 0..7
#pragma unroll
  for (int i = 0; i < 4; ++i) {
    int kk = bk * 32 + ty + i * 8;
    tile[ty + i * 8][tx] = W[(size_t)kk * Ndim + bn * 32 + tx];
  }
  __syncthreads();
#pragma unroll
  for (int i = 0; i < 4; ++i) {
    int nn = bn * 32 + ty + i * 8;
    Wt[(size_t)nn * Kdim + bk * 32 + tx] = (__bf16)tile[tx][ty + i * 8];
  }
}

// ---------------- GEMM: out = tanh(A @ Wt^T + b) ---------------------------
typedef const __attribute__((address_space(1))) void* gptr1;
typedef __attribute__((address_space(3))) void* lptr3;

__device__ __forceinline__ void gld_lds16(const __bf16* g, __bf16* l) {
  __builtin_amdgcn_global_load_lds((gptr1)g, (lptr3)l, 16, 0, 0);
}

__global__ __launch_bounds__(256) void gemm_tanh_kernel(
    const __bf16* __restrict__ A,    // [M][K] feats
    const __bf16* __restrict__ Bt,   // [N][K] W^T
    const float* __restrict__ bias,  // [N]
    float* __restrict__ out) {       // [M][N]
  __shared__ __align__(16) __bf16 smA[128 * 32];
  __shared__ __align__(16) __bf16 smB[128 * 32];

  const int tid = threadIdx.x;
  const int wv = tid >> 6;
  const int lane = tid & 63;
  const int m0 = blockIdx.y * 128;
  const int n0 = blockIdx.x * 128;

  // staging: 2 rounds of (256 threads x 16B) per tile; row = tid/4, col8 = tid%4
  const int srow = tid >> 2;
  const int scol = (tid & 3) * 8;
  const __bf16* gA0 = A + (size_t)(m0 + srow) * Kdim + scol;
  const __bf16* gA1 = gA0 + (size_t)64 * Kdim;
  const __bf16* gB0 = Bt + (size_t)(n0 + srow) * Kdim + scol;
  const __bf16* gB1 = gB0 + (size_t)64 * Kdim;
  // wave-uniform LDS bases (HW adds lane*16 bytes)
  __bf16* lA0 = smA + wv * 512;
  __bf16* lA1 = smA + 2048 + wv * 512;
  __bf16* lB0 = smB + wv * 512;
  __bf16* lB1 = smB + 2048 + wv * 512;

  const int wm = (wv >> 1) * 64;
  const int wn = (wv & 1) * 64;
  const int lr = lane & 15;
  const int lq = lane >> 4;

  int aoff[4], boff[4];
#pragma unroll
  for (int i = 0; i < 4; ++i) {
    aoff[i] = (wm + i * 16 + lr) * 32 + lq * 8;
    boff[i] = (wn + i * 16 + lr) * 32 + lq * 8;
  }

  f32x4 acc[4][4];
#pragma unroll
  for (int i = 0; i < 4; ++i)
#pragma unroll
    for (int j = 0; j < 4; ++j) acc[i][j] = (f32x4){0.f, 0.f, 0.f, 0.f};

  for (int k0 = 0; k0 < Kdim; k0 += 32) {
    __syncthreads();
    gld_lds16(gA0 + k0, lA0);
    gld_lds16(gA1 + k0, lA1);
    gld_lds16(gB0 + k0, lB0);
    gld_lds16(gB1 + k0, lB1);
    __syncthreads();

    b16x8 av[4], bv[4];
#pragma unroll
    for (int i = 0; i < 4; ++i) av[i] = *reinterpret_cast<const b16x8*>(smA + aoff[i]);
#pragma unroll
    for (int i = 0; i < 4; ++i) bv[i] = *reinterpret_cast<const b16x8*>(smB + boff[i]);
#pragma unroll
    for (int i = 0; i < 4; ++i)
#pragma unroll
      for (int j = 0; j < 4; ++j)
        acc[i][j] = __builtin_amdgcn_mfma_f32_16x16x32_bf16(av[i], bv[j], acc[i][j], 0, 0, 0);
  }

  // epilogue: C/D layout col=lane&15, row=(lane>>4)*4+reg
#pragma unroll
  for (int j = 0; j < 4; ++j) {
    int gn = n0 + wn + j * 16 + lr;
    float bval = bias[gn];
#pragma unroll
    for (int i = 0; i < 4; ++i) {
      int gmb = m0 + wm + i * 16 + lq * 4;
#pragma unroll
      for (int r = 0; r < 4; ++r) {
        float v = acc[i][j][r] + bval;
        out[(size_t)(gmb + r) * Ndim + gn] = fast_tanh(v);
      }
    }
  }
}

// ---------------------------------------------------------------------------
extern "C" void kernel_launch(void* const* d_in, const int* in_sizes, int n_in,
                              void* d_out, int out_size, void* d_ws, size_t ws_size,
                              hipStream_t stream) {
  const float* x = (const float*)d_in[0];
  const float* W = (const float*)d_in[1];
  const float* b = (const float*)d_in[2];
  float* out = (float*)d_out;

  // ws layout: Wt bf16 [N*K] (16.8 MB) | feats bf16 [M*K] (134 MB)
  __bf16* Wt = (__bf16*)d_ws;
  __bf16* feats = Wt + (size_t)Ndim * Kdim;

  hipLaunchKernelGGL(feats_kernel, dim3(Mdim * Fdim / 4 / 256), dim3(256), 0,
                     stream, x, feats);
  hipLaunchKernelGGL(wtrans_kernel, dim3(Ndim / 32, Kdim / 32), dim3(32, 8), 0,
                     stream, W, Wt);
  hipLaunchKernelGGL(gemm_tanh_kernel, dim3(Ndim / 128, Mdim / 128), dim3(256),
                     0, stream, feats, Wt, b, out);
}

// Round 2
// 652.528 us; speedup vs baseline: 1.0097x; 1.0097x over previous
//
#include <hip/hip_runtime.h>
#include <hip/hip_bf16.h>
#include <math.h>

// ---------------------------------------------------------------------------
// QuantumProcessingLayer: out = tanh(concat(f(x), f(x)^2) @ W + b)
//   f(x) = tanh(2pi x) + 0.1*sin(2pi x)*cos(pi x)
// M=16384 (B*S), F=2048, K=4096 (2F), N=2048 (U). fp32 in/out, bf16 MFMA core.
// R2: XOR bank-conflict swizzle in GEMM LDS; 16B-store prologue.
// ---------------------------------------------------------------------------

typedef __bf16 b16x8 __attribute__((ext_vector_type(8)));
typedef float f32x4 __attribute__((ext_vector_type(4)));

constexpr int Mdim = 16384;
constexpr int Fdim = 2048;
constexpr int Kdim = 4096;
constexpr int Ndim = 2048;

#define TWO_PI_F 6.28318530717958647692f

__device__ __forceinline__ float fast_tanh(float x) {
  float ax = fabsf(x);
  float e = __expf(-2.0f * ax);
  float t = (1.0f - e) / (1.0f + e);
  return copysignf(t, x);
}

// ---------------- prologue: feats[m][k] (bf16), k<F: qe, k>=F: qe^2 ---------
struct __align__(16) B8 { __bf16 v[8]; };

__global__ void feats_kernel(const float* __restrict__ x, __bf16* __restrict__ feats) {
  int idx = blockIdx.x * blockDim.x + threadIdx.x;  // one thread per 8 elems
  long i8 = (long)idx << 3;
  float4 xv0 = reinterpret_cast<const float4*>(x)[idx * 2];
  float4 xv1 = reinterpret_cast<const float4*>(x)[idx * 2 + 1];
  float q[8] = {xv0.x, xv0.y, xv0.z, xv0.w, xv1.x, xv1.y, xv1.z, xv1.w};
  B8 qe, en;
#pragma unroll
  for (int j = 0; j < 8; ++j) {
    float qp = TWO_PI_F * q[j];
    float t = fast_tanh(qp);
    float v = t + 0.1f * (__sinf(qp) * __cosf(0.5f * qp));
    qe.v[j] = (__bf16)v;
    en.v[j] = (__bf16)(v * v);
  }
  int m = (int)(i8 >> 11);     // / Fdim
  int f = (int)(i8 & (Fdim - 1));
  size_t base = (size_t)m * Kdim + f;
  *reinterpret_cast<B8*>(feats + base) = qe;
  *reinterpret_cast<B8*>(feats + base + Fdim) = en;
}

// ---------------- W [K][N] fp32  ->  Wt [N][K] bf16 ------------------------
__global__ void wtrans_kernel(const float* __restrict__ W, __bf16* __restrict__ Wt) {
  __shared__ float tile[32][33];
  int bn = blockIdx.x;   // N/32 = 64
  int bk = blockIdx.y;   // K/32 = 128
  int tx = threadIdx.x;  // 0..31
  int ty = threadIdx.y;  // 0..7
#pragma unroll
  for (int i = 0; i < 4; ++i) {
    int kk = bk * 32 + ty + i * 8;
    tile[ty + i * 8][tx] = W[(size_t)kk * Ndim + bn * 32 + tx];
  }
  __syncthreads();
#pragma unroll
  for (int i = 0; i < 4; ++i) {
    int nn = bn * 32 + ty + i * 8;
    Wt[(size_t)nn * Kdim + bk * 32 + tx] = (__bf16)tile[tx][ty + i * 8];
  }
}

// ---------------- GEMM: out = tanh(A @ Wt^T + b) ---------------------------
typedef const __attribute__((address_space(1))) void* gptr1;
typedef __attribute__((address_space(3))) void* lptr3;

__device__ __forceinline__ void gld_lds16(const __bf16* g, __bf16* l) {
  __builtin_amdgcn_global_load_lds((gptr1)g, (lptr3)l, 16, 0, 0);
}

// LDS layout (per 128x32 tile): element (row, k) lives at
//   row*32 + (chunk ^ ((row>>1)&3))*8 + (k&7),  chunk = k>>3.
// Staging DMA writes chunk index == tid (fixed), so thread tid sources the
// global chunk ((tid&3) ^ ((srow>>1)&3)) of its row — coalescing preserved
// within each row's 64B segment. Fragment reads land each 16-lane quadrant on
// all 8 (parity x chunk) bank groups exactly twice => free 2-way only.
__global__ __launch_bounds__(256) void gemm_tanh_kernel(
    const __bf16* __restrict__ A,    // [M][K] feats
    const __bf16* __restrict__ Bt,   // [N][K] W^T
    const float* __restrict__ bias,  // [N]
    float* __restrict__ out) {       // [M][N]
  __shared__ __align__(16) __bf16 smA[128 * 32];
  __shared__ __align__(16) __bf16 smB[128 * 32];

  const int tid = threadIdx.x;
  const int wv = tid >> 6;
  const int lane = tid & 63;
  const int m0 = blockIdx.y * 128;
  const int n0 = blockIdx.x * 128;

  // staging: 2 rounds of (256 threads x 16B) per tile; row = tid/4
  const int srow = tid >> 2;
  const int scol = (((tid & 3) ^ ((srow >> 1) & 3))) * 8;  // XOR-swizzled source chunk
  const __bf16* gA0 = A + (size_t)(m0 + srow) * Kdim + scol;
  const __bf16* gA1 = gA0 + (size_t)64 * Kdim;
  const __bf16* gB0 = Bt + (size_t)(n0 + srow) * Kdim + scol;
  const __bf16* gB1 = gB0 + (size_t)64 * Kdim;
  // wave-uniform LDS bases (HW adds lane*16 bytes)
  __bf16* lA0 = smA + wv * 512;
  __bf16* lA1 = smA + 2048 + wv * 512;
  __bf16* lB0 = smB + wv * 512;
  __bf16* lB1 = smB + 2048 + wv * 512;

  const int wm = (wv >> 1) * 64;
  const int wn = (wv & 1) * 64;
  const int lr = lane & 15;
  const int lq = lane >> 4;
  const int swz = (lr >> 1) & 3;          // row bits 1..2 == lr bits 1..2
  const int kchunk = (lq ^ swz) * 8;      // swizzled k-chunk for fragment reads

  int aoff[4], boff[4];
#pragma unroll
  for (int i = 0; i < 4; ++i) {
    aoff[i] = (wm + i * 16 + lr) * 32 + kchunk;
    boff[i] = (wn + i * 16 + lr) * 32 + kchunk;
  }

  f32x4 acc[4][4];
#pragma unroll
  for (int i = 0; i < 4; ++i)
#pragma unroll
    for (int j = 0; j < 4; ++j) acc[i][j] = (f32x4){0.f, 0.f, 0.f, 0.f};

  for (int k0 = 0; k0 < Kdim; k0 += 32) {
    __syncthreads();
    gld_lds16(gA0 + k0, lA0);
    gld_lds16(gA1 + k0, lA1);
    gld_lds16(gB0 + k0, lB0);
    gld_lds16(gB1 + k0, lB1);
    __syncthreads();

    b16x8 av[4], bv[4];
#pragma unroll
    for (int i = 0; i < 4; ++i) av[i] = *reinterpret_cast<const b16x8*>(smA + aoff[i]);
#pragma unroll
    for (int i = 0; i < 4; ++i) bv[i] = *reinterpret_cast<const b16x8*>(smB + boff[i]);
#pragma unroll
    for (int i = 0; i < 4; ++i)
#pragma unroll
      for (int j = 0; j < 4; ++j)
        acc[i][j] = __builtin_amdgcn_mfma_f32_16x16x32_bf16(av[i], bv[j], acc[i][j], 0, 0, 0);
  }

  // epilogue: C/D layout col=lane&15, row=(lane>>4)*4+reg
#pragma unroll
  for (int j = 0; j < 4; ++j) {
    int gn = n0 + wn + j * 16 + lr;
    float bval = bias[gn];
#pragma unroll
    for (int i = 0; i < 4; ++i) {
      int gmb = m0 + wm + i * 16 + lq * 4;
#pragma unroll
      for (int r = 0; r < 4; ++r) {
        float v = acc[i][j][r] + bval;
        out[(size_t)(gmb + r) * Ndim + gn] = fast_tanh(v);
      }
    }
  }
}

// ---------------------------------------------------------------------------
extern "C" void kernel_launch(void* const* d_in, const int* in_sizes, int n_in,
                              void* d_out, int out_size, void* d_ws, size_t ws_size,
                              hipStream_t stream) {
  const float* x = (const float*)d_in[0];
  const float* W = (const float*)d_in[1];
  const float* b = (const float*)d_in[2];
  float* out = (float*)d_out;

  // ws layout: Wt bf16 [N*K] (16.8 MB) | feats bf16 [M*K] (134 MB)
  __bf16* Wt = (__bf16*)d_ws;
  __bf16* feats = Wt + (size_t)Ndim * Kdim;

  hipLaunchKernelGGL(feats_kernel, dim3(Mdim * Fdim / 8 / 256), dim3(256), 0,
                     stream, x, feats);
  hipLaunchKernelGGL(wtrans_kernel, dim3(Ndim / 32, Kdim / 32), dim3(32, 8), 0,
                     stream, W, Wt);
  hipLaunchKernelGGL(gemm_tanh_kernel, dim3(Ndim / 128, Mdim / 128), dim3(256),
                     0, stream, feats, Wt, b, out);
}

// Round 3
// 576.934 us; speedup vs baseline: 1.1420x; 1.1310x over previous
//
#include <hip/hip_runtime.h>
#include <hip/hip_bf16.h>
#include <math.h>

// ---------------------------------------------------------------------------
// QuantumProcessingLayer: out = tanh(concat(f(x), f(x)^2) @ W + b)
//   f(x) = tanh(2pi x) + 0.1*sin(2pi x)*cos(pi x)
// M=16384 (B*S), F=2048, K=4096 (2F), N=2048 (U). fp32 in/out, bf16 MFMA core.
// R3: single-barrier double-buffered GEMM pipeline (DMA(k+1) in flight during
//     compute(k)); hardware v_sin/v_cos/v_rcp prologue.
// ---------------------------------------------------------------------------

typedef __bf16 b16x8 __attribute__((ext_vector_type(8)));
typedef float f32x4 __attribute__((ext_vector_type(4)));

constexpr int Mdim = 16384;
constexpr int Fdim = 2048;
constexpr int Kdim = 4096;
constexpr int Ndim = 2048;

// tanh(2*pi*x): e = exp(-4*pi*|x|); t = (1-e)/(1+e) via v_rcp
__device__ __forceinline__ float tanh_2pix(float x) {
  float ax = fabsf(x);
  float e = __expf(-12.566370614359172f * ax);
  float t = (1.0f - e) * __builtin_amdgcn_rcpf(1.0f + e);
  return copysignf(t, x);
}

__device__ __forceinline__ float fast_tanh(float x) {
  float ax = fabsf(x);
  float e = __expf(-2.0f * ax);
  float t = (1.0f - e) * __builtin_amdgcn_rcpf(1.0f + e);
  return copysignf(t, x);
}

// ---------------- prologue: feats[m][k] (bf16), k<F: qe, k>=F: qe^2 ---------
struct __align__(16) B8 { __bf16 v[8]; };

__global__ void feats_kernel(const float* __restrict__ x, __bf16* __restrict__ feats) {
  int idx = blockIdx.x * blockDim.x + threadIdx.x;  // one thread per 8 elems
  long i8 = (long)idx << 3;
  float4 xv0 = reinterpret_cast<const float4*>(x)[idx * 2];
  float4 xv1 = reinterpret_cast<const float4*>(x)[idx * 2 + 1];
  float q[8] = {xv0.x, xv0.y, xv0.z, xv0.w, xv1.x, xv1.y, xv1.z, xv1.w};
  B8 qe, en;
#pragma unroll
  for (int j = 0; j < 8; ++j) {
    float xx = q[j];
    // sin(2*pi*x) = v_sin(x revolutions); cos(pi*x) = v_cos(x/2 revolutions)
    float s = __builtin_amdgcn_sinf(xx);
    float c = __builtin_amdgcn_cosf(0.5f * xx);
    float v = tanh_2pix(xx) + 0.1f * s * c;
    qe.v[j] = (__bf16)v;
    en.v[j] = (__bf16)(v * v);
  }
  int m = (int)(i8 >> 11);     // / Fdim
  int f = (int)(i8 & (Fdim - 1));
  size_t base = (size_t)m * Kdim + f;
  *reinterpret_cast<B8*>(feats + base) = qe;
  *reinterpret_cast<B8*>(feats + base + Fdim) = en;
}

// ---------------- W [K][N] fp32  ->  Wt [N][K] bf16 ------------------------
__global__ void wtrans_kernel(const float* __restrict__ W, __bf16* __restrict__ Wt) {
  __shared__ float tile[32][33];
  int bn = blockIdx.x;   // N/32 = 64
  int bk = blockIdx.y;   // K/32 = 128
  int tx = threadIdx.x;  // 0..31
  int ty = threadIdx.y;  // 0..7
#pragma unroll
  for (int i = 0; i < 4; ++i) {
    int kk = bk * 32 + ty + i * 8;
    tile[ty + i * 8][tx] = W[(size_t)kk * Ndim + bn * 32 + tx];
  }
  __syncthreads();
#pragma unroll
  for (int i = 0; i < 4; ++i) {
    int nn = bn * 32 + ty + i * 8;
    Wt[(size_t)nn * Kdim + bk * 32 + tx] = (__bf16)tile[tx][ty + i * 8];
  }
}

// ---------------- GEMM: out = tanh(A @ Wt^T + b) ---------------------------
typedef const __attribute__((address_space(1))) void* gptr1;
typedef __attribute__((address_space(3))) void* lptr3;

__device__ __forceinline__ void gld_lds16(const __bf16* g, __bf16* l) {
  __builtin_amdgcn_global_load_lds((gptr1)g, (lptr3)l, 16, 0, 0);
}

// Pipeline: one __syncthreads per k-step. At the barrier: (a) DMA into the
// current buffer has drained (vmcnt(0) before s_barrier), (b) every wave is
// done reading the other buffer. Then issue DMA(k+1) into the other buffer
// and compute(k) — the prefetch is in flight during the whole compute phase,
// so its latency is hidden behind MFMA instead of serialized before it.
// LDS element (row,k) at row*32 + (chunk ^ ((row>>1)&3))*8 + (k&7) (XOR
// swizzle, conflicts measured 0 in R2).
__global__ __launch_bounds__(256, 4) void gemm_tanh_kernel(
    const __bf16* __restrict__ A,    // [M][K] feats
    const __bf16* __restrict__ Bt,   // [N][K] W^T
    const float* __restrict__ bias,  // [N]
    float* __restrict__ out) {       // [M][N]
  __shared__ __align__(16) __bf16 smem[4 * 4096];  // A0 | B0 | A1 | B1
  __bf16* const sA0 = smem;
  __bf16* const sB0 = smem + 4096;
  __bf16* const sA1 = smem + 8192;
  __bf16* const sB1 = smem + 12288;

  const int tid = threadIdx.x;
  const int wv = tid >> 6;
  const int lane = tid & 63;
  const int m0 = blockIdx.y * 128;
  const int n0 = blockIdx.x * 128;

  // staging: 2 rounds of (256 threads x 16B) per tile; row = tid/4
  const int srow = tid >> 2;
  const int scol = (((tid & 3) ^ ((srow >> 1) & 3))) * 8;  // XOR-swizzled source chunk
  const __bf16* gA0 = A + (size_t)(m0 + srow) * Kdim + scol;
  const __bf16* gA1 = gA0 + (size_t)64 * Kdim;
  const __bf16* gB0 = Bt + (size_t)(n0 + srow) * Kdim + scol;
  const __bf16* gB1 = gB0 + (size_t)64 * Kdim;
  const int ldsoff = wv * 512;  // wave-uniform LDS base (HW adds lane*16B)

  const int wm = (wv >> 1) * 64;
  const int wn = (wv & 1) * 64;
  const int lr = lane & 15;
  const int lq = lane >> 4;
  const int swz = (lr >> 1) & 3;
  const int kchunk = (lq ^ swz) * 8;

  int aoff[4], boff[4];
#pragma unroll
  for (int i = 0; i < 4; ++i) {
    aoff[i] = (wm + i * 16 + lr) * 32 + kchunk;
    boff[i] = (wn + i * 16 + lr) * 32 + kchunk;
  }

  f32x4 acc[4][4];
#pragma unroll
  for (int i = 0; i < 4; ++i)
#pragma unroll
    for (int j = 0; j < 4; ++j) acc[i][j] = (f32x4){0.f, 0.f, 0.f, 0.f};

  auto stage = [&](int k0, __bf16* dA, __bf16* dB) {
    gld_lds16(gA0 + k0, dA + ldsoff);
    gld_lds16(gA1 + k0, dA + 2048 + ldsoff);
    gld_lds16(gB0 + k0, dB + ldsoff);
    gld_lds16(gB1 + k0, dB + 2048 + ldsoff);
  };
  auto compute = [&](const __bf16* cA, const __bf16* cB) {
    b16x8 av[4], bv[4];
#pragma unroll
    for (int i = 0; i < 4; ++i) av[i] = *reinterpret_cast<const b16x8*>(cA + aoff[i]);
#pragma unroll
    for (int i = 0; i < 4; ++i) bv[i] = *reinterpret_cast<const b16x8*>(cB + boff[i]);
#pragma unroll
    for (int i = 0; i < 4; ++i)
#pragma unroll
      for (int j = 0; j < 4; ++j)
        acc[i][j] = __builtin_amdgcn_mfma_f32_16x16x32_bf16(av[i], bv[j], acc[i][j], 0, 0, 0);
  };

  stage(0, sA0, sB0);
  for (int k0 = 0; k0 < Kdim; k0 += 64) {
    __syncthreads();
    if (k0 + 32 < Kdim) stage(k0 + 32, sA1, sB1);
    compute(sA0, sB0);
    __syncthreads();
    if (k0 + 64 < Kdim) stage(k0 + 64, sA0, sB0);
    compute(sA1, sB1);
  }

  // epilogue: C/D layout col=lane&15, row=(lane>>4)*4+reg
#pragma unroll
  for (int j = 0; j < 4; ++j) {
    int gn = n0 + wn + j * 16 + lr;
    float bval = bias[gn];
#pragma unroll
    for (int i = 0; i < 4; ++i) {
      int gmb = m0 + wm + i * 16 + lq * 4;
#pragma unroll
      for (int r = 0; r < 4; ++r) {
        float v = acc[i][j][r] + bval;
        out[(size_t)(gmb + r) * Ndim + gn] = fast_tanh(v);
      }
    }
  }
}

// ---------------------------------------------------------------------------
extern "C" void kernel_launch(void* const* d_in, const int* in_sizes, int n_in,
                              void* d_out, int out_size, void* d_ws, size_t ws_size,
                              hipStream_t stream) {
  const float* x = (const float*)d_in[0];
  const float* W = (const float*)d_in[1];
  const float* b = (const float*)d_in[2];
  float* out = (float*)d_out;

  // ws layout: Wt bf16 [N*K] (16.8 MB) | feats bf16 [M*K] (134 MB)
  __bf16* Wt = (__bf16*)d_ws;
  __bf16* feats = Wt + (size_t)Ndim * Kdim;

  hipLaunchKernelGGL(feats_kernel, dim3(Mdim * Fdim / 8 / 256), dim3(256), 0,
                     stream, x, feats);
  hipLaunchKernelGGL(wtrans_kernel, dim3(Ndim / 32, Kdim / 32), dim3(32, 8), 0,
                     stream, W, Wt);
  hipLaunchKernelGGL(gemm_tanh_kernel, dim3(Ndim / 128, Mdim / 128), dim3(256),
                     0, stream, feats, Wt, b, out);
}